// Round 3
// baseline (301.808 us; speedup 1.0000x reference)
//
#include <hip/hip_runtime.h>
#include <cstddef>

#define B_  16
#define C_  512
#define N_  1024

typedef __attribute__((ext_vector_type(8))) __bf16 bf16x8;
typedef __attribute__((ext_vector_type(4))) float f32x4;
typedef __attribute__((ext_vector_type(4))) short s16x4;

__device__ __forceinline__ unsigned short f2bf(float x) {
  unsigned u = __float_as_uint(x);
  return (unsigned short)((u + 0x7fffu + ((u >> 16) & 1u)) >> 16);
}
__device__ __forceinline__ float bf2f(unsigned short h) {
  return __uint_as_float(((unsigned)h) << 16);
}

#define GLDS16(g, l)                                                            \
  __builtin_amdgcn_global_load_lds(                                             \
      (const __attribute__((address_space(1))) void*)(g),                       \
      (__attribute__((address_space(3))) void*)(l), 16, 0, 0)

// ---------- weight fp32 -> bf16 ----------
__global__ __launch_bounds__(256) void wconv_kernel(
    const float* __restrict__ wq, const float* __restrict__ wp,
    unsigned short* __restrict__ oq, unsigned short* __restrict__ op) {
  int i = blockIdx.x * 256 + threadIdx.x;  // float4 chunks
  const float4* src; unsigned short* dst; int off;
  if (i < 196608) { src = (const float4*)wq; dst = oq; off = i; }
  else            { src = (const float4*)wp; dst = op; off = i - 196608; }
  float4 v = src[off];
  union { unsigned short s[4]; ushort4 u; } o;
  o.s[0] = f2bf(v.x); o.s[1] = f2bf(v.y);
  o.s[2] = f2bf(v.z); o.s[3] = f2bf(v.w);
  *(ushort4*)(dst + (size_t)off * 4) = o.u;
}

// ---------- GroupNorm: writes hT[b][n][c] bf16 ----------
__global__ __launch_bounds__(256) void gn_kernel(
    const float* __restrict__ x, const float* __restrict__ gamma,
    const float* __restrict__ beta, unsigned short* __restrict__ hT) {
  int bg = blockIdx.x;
  int b = bg >> 5, g = bg & 31;
  size_t base = ((size_t)b * C_ + (size_t)g * 16) * N_;
  const float4* x4 = (const float4*)(x + base);
  int tid = threadIdx.x;

  float sum = 0.f, sq = 0.f;
  float4 vv[16];
#pragma unroll
  for (int i = 0; i < 16; i++) {
    float4 v = x4[tid + i * 256];
    vv[i] = v;
    sum += v.x + v.y + v.z + v.w;
    sq  += v.x * v.x + v.y * v.y + v.z * v.z + v.w * v.w;
  }
#pragma unroll
  for (int off = 32; off > 0; off >>= 1) {
    sum += __shfl_down(sum, off, 64);
    sq  += __shfl_down(sq, off, 64);
  }
  __shared__ float sm[4], sv[4];
  int lane = tid & 63, w = tid >> 6;
  if (lane == 0) { sm[w] = sum; sv[w] = sq; }
  __syncthreads();
  if (tid == 0) {
    float s = sm[0] + sm[1] + sm[2] + sm[3];
    float q = sv[0] + sv[1] + sv[2] + sv[3];
    float mean = s * (1.f / 16384.f);
    float var  = q * (1.f / 16384.f) - mean * mean;
    sm[0] = mean;
    sv[0] = rsqrtf(var + 1e-5f);
  }
  __syncthreads();
  float mean = sm[0], rstd = sv[0];

  union { unsigned short s[16]; uint4 u[2]; } row[4];
#pragma unroll
  for (int i = 0; i < 16; i++) {
    int c = g * 16 + i;
    float ga = gamma[c] * rstd;
    float be = beta[c] - mean * ga;
    float4 v = vv[i];
    row[0].s[i] = f2bf(v.x * ga + be);
    row[1].s[i] = f2bf(v.y * ga + be);
    row[2].s[i] = f2bf(v.z * ga + be);
    row[3].s[i] = f2bf(v.w * ga + be);
  }
#pragma unroll
  for (int j = 0; j < 4; j++) {
    uint4* dst = (uint4*)(hT + ((size_t)b * N_ + 4 * tid + j) * C_ + g * 16);
    dst[0] = row[j].u[0];
    dst[1] = row[j].u[1];
  }
}

// ---------- MFMA GEMM: Out[b,m,n] = sum_k W[m,k]*InT[b,n,k] + bias[m] (+resid) ----------
// OUT_BF16==1 (QKV): K rows (m in [512,1024)) are written TRANSPOSED into the K
// region as KT[b][n][m-512]. The transpose goes through an LDS staging buffer
// (rows padded to 136 shorts = 16B aligned) so the global writes are 256B
// contiguous per n instead of scattered 8B stores.
template <int OUT_BF16>
__global__ __launch_bounds__(256) void gemm_mfma(
    const unsigned short* __restrict__ Wb, const float* __restrict__ bias,
    const unsigned short* __restrict__ InT, const float* __restrict__ resid,
    void* __restrict__ Out, int M) {
  __shared__ __align__(16) unsigned short SH[2][128 * 34];  // As=SH[0], Bs=SH[1]; epi aliases both

  const int b = blockIdx.z;
  const int n0 = blockIdx.x * 128, m0 = blockIdx.y * 128;
  const int tid = threadIdx.x;
  const int lane = tid & 63, wave = tid >> 6;
  const int col = lane & 15, quad = lane >> 4;
  const int wm = (wave >> 1) << 6, wn = (wave & 1) << 6;

  const unsigned short* Ag = Wb + (size_t)m0 * C_;
  const unsigned short* Bg = InT + ((size_t)b * N_ + n0) * C_;

  const int r0 = tid >> 2, c0 = (tid & 3) << 3;

  f32x4 acc[4][4];
#pragma unroll
  for (int i = 0; i < 4; i++)
#pragma unroll
    for (int j = 0; j < 4; j++) acc[i][j] = f32x4{0.f, 0.f, 0.f, 0.f};

  for (int k0 = 0; k0 < C_; k0 += 32) {
    __syncthreads();
    GLDS16(Ag + (size_t)r0 * C_ + k0 + c0,        &SH[0][tid * 8]);
    GLDS16(Ag + (size_t)(r0 + 64) * C_ + k0 + c0, &SH[0][(tid + 256) * 8]);
    GLDS16(Bg + (size_t)r0 * C_ + k0 + c0,        &SH[1][tid * 8]);
    GLDS16(Bg + (size_t)(r0 + 64) * C_ + k0 + c0, &SH[1][(tid + 256) * 8]);
    __syncthreads();

    bf16x8 af[4], bfr[4];
#pragma unroll
    for (int mt = 0; mt < 4; mt++)
      af[mt] = *(const bf16x8*)&SH[0][(wm + mt * 16 + col) * 32 + quad * 8];
#pragma unroll
    for (int nt = 0; nt < 4; nt++)
      bfr[nt] = *(const bf16x8*)&SH[1][(wn + nt * 16 + col) * 32 + quad * 8];
#pragma unroll
    for (int mt = 0; mt < 4; mt++)
#pragma unroll
      for (int nt = 0; nt < 4; nt++)
        acc[mt][nt] = __builtin_amdgcn_mfma_f32_16x16x32_bf16(
            af[mt], bfr[nt], acc[mt][nt], 0, 0, 0);
  }

  const bool kT = OUT_BF16 && (m0 >= 512) && (m0 < 1024);

  if (kT) {
    // Transposed K output via LDS: epi[64 n][136 shorts] per n-half.
    unsigned short* epi = &SH[0][0];
    unsigned short* kt_out =
        (unsigned short*)Out + ((size_t)b * 1536 + 512) * N_ + (m0 - 512);
#pragma unroll
    for (int hf = 0; hf < 2; hf++) {
      __syncthreads();
      if ((wave & 1) == hf) {
#pragma unroll
        for (int mt = 0; mt < 4; mt++) {
          int mloc = wm + mt * 16 + quad * 4;      // 0..127 within block tile
          int mabs = m0 + mloc;
#pragma unroll
          for (int nt = 0; nt < 4; nt++) {
            union { unsigned short s[4]; ushort4 v; } o;
#pragma unroll
            for (int r = 0; r < 4; r++)
              o.s[r] = f2bf(acc[mt][nt][r] + bias[mabs + r]);
            *(ushort4*)&epi[(nt * 16 + col) * 136 + mloc] = o.v;
          }
        }
      }
      __syncthreads();
#pragma unroll
      for (int pass = 0; pass < 4; pass++) {
        int n_l = (tid >> 4) + pass * 16;
        int ch = tid & 15;
        uint4 v = *(const uint4*)&epi[n_l * 136 + ch * 8];
        *(uint4*)(kt_out + (size_t)(n0 + hf * 64 + n_l) * 512 + ch * 8) = v;
      }
    }
    return;
  }

#pragma unroll
  for (int mt = 0; mt < 4; mt++) {
    int mbase = m0 + wm + mt * 16 + quad * 4;
#pragma unroll
    for (int nt = 0; nt < 4; nt++) {
      int n = n0 + wn + nt * 16 + col;
      if constexpr (OUT_BF16) {
#pragma unroll
        for (int r = 0; r < 4; r++) {
          float v = acc[mt][nt][r] + bias[mbase + r];
          ((unsigned short*)Out)[((size_t)b * M + mbase + r) * N_ + n] = f2bf(v);
        }
      } else {
#pragma unroll
        for (int r = 0; r < 4; r++) {
          int m = mbase + r;
          float v = acc[mt][nt][r] + bias[m];
          size_t off = ((size_t)b * M + m) * N_ + n;
          ((float*)Out)[off] = v + resid[off];
        }
      }
    }
  }
}

// ---------- MFMA flash attention, no-max softmax ----------
// K pre-transposed KT[b][key][512]; V native [d][N] (both 128B/row per head
// tile). Reg-staged (global->VGPR->ds_write) into PADDED LDS so the row index
// reaches the bank: Kt stride 72 shorts (144B, 16B-aligned b128 R/W), Vs
// stride 68 shorts (136B, b64 R/W). This removes the structural 2-way quarter-
// wave conflict of 128B-stride rows (round-2's residual 2^21 conflicts).
// Double-buffered, loads issued at tile top, ds_writes after compute (T14),
// one barrier per tile. Grid: 1024 blocks (8 q-blocks x 128 bh), XCD-grouped
// so all q-blocks of one (b,h) share one XCD's L2.
__device__ __forceinline__ void attn_tile(const bf16x8 (&qf)[2][2],
                                          const bf16x8 (&kf)[4][2],
                                          const s16x4 (&vf)[4][4],
                                          f32x4 (&O)[4][2], float (&l_i)[2]) {
#pragma unroll
  for (int nt = 0; nt < 2; nt++) {
    f32x4 sf[4];
#pragma unroll
    for (int mt = 0; mt < 4; mt++) sf[mt] = f32x4{0.f, 0.f, 0.f, 0.f};
    __builtin_amdgcn_s_setprio(1);
#pragma unroll
    for (int ks = 0; ks < 2; ks++)
#pragma unroll
      for (int mt = 0; mt < 4; mt++)
        sf[mt] = __builtin_amdgcn_mfma_f32_16x16x32_bf16(
            kf[mt][ks], qf[nt][ks], sf[mt], 0, 0, 0);
    __builtin_amdgcn_s_setprio(0);

    // p = exp(s); pack to bf16 by truncation (1 v_perm per pair)
    s16x4 pb[4];
    float lsum = 0.f;
#pragma unroll
    for (int kc = 0; kc < 4; kc++) {
      float e0 = __expf(sf[kc][0]);
      float e1 = __expf(sf[kc][1]);
      float e2 = __expf(sf[kc][2]);
      float e3 = __expf(sf[kc][3]);
      lsum += (e0 + e1) + (e2 + e3);
      unsigned lo = __builtin_amdgcn_perm(__float_as_uint(e1), __float_as_uint(e0), 0x07060302u);
      unsigned hi = __builtin_amdgcn_perm(__float_as_uint(e3), __float_as_uint(e2), 0x07060302u);
      union { unsigned u[2]; s16x4 v; } t;
      t.u[0] = lo; t.u[1] = hi;
      pb[kc] = t.v;
    }
    l_i[nt] += lsum;

    __builtin_amdgcn_s_setprio(1);
#pragma unroll
    for (int kc = 0; kc < 4; kc++)
#pragma unroll
      for (int mt = 0; mt < 4; mt++)
        O[mt][nt] = __builtin_amdgcn_mfma_f32_16x16x16bf16_1k(
            vf[mt][kc], pb[kc], O[mt][nt], 0, 0, 0);
    __builtin_amdgcn_s_setprio(0);
  }
}

__global__ __launch_bounds__(256, 4) void attn_mfma(
    const unsigned short* __restrict__ qkv, unsigned short* __restrict__ aoT) {
  __shared__ __align__(16) unsigned short Kt[2][64 * 72];
  __shared__ __align__(16) unsigned short Vs[2][64 * 68];

  const int tid = threadIdx.x;
  const int wave = tid >> 6, lane = tid & 63;
  const int quad = lane >> 4, col = lane & 15;
  const int bi = blockIdx.x;
  const int hh = bi & 7, qb = (bi >> 3) & 7, b = bi >> 6;  // XCD = bi&7 = head
  const int qblk = qb * 128 + wave * 32;

  const unsigned short* qp  = qkv + ((size_t)b * 1536 + hh * 64) * N_;          // [d][N]
  const unsigned short* ktp = qkv + ((size_t)b * 1536 + 512) * N_ + hh * 64;    // [key][512]
  const unsigned short* vp  = qkv + ((size_t)b * 1536 + 1024 + hh * 64) * N_;   // [d][N]

  const int sr0 = tid >> 3, sc0 = tid & 7;  // staging: row 0..31, 16B chunk 0..7

  // Q B-fragments pre-scaled by 0.125 (exact: exponent shift under RNE).
  bf16x8 qf[2][2];
#pragma unroll
  for (int nt = 0; nt < 2; nt++) {
    int qg = qblk + nt * 16 + col;
#pragma unroll
    for (int ks = 0; ks < 2; ks++) {
      union { unsigned short s[8]; bf16x8 v; } t;
#pragma unroll
      for (int j = 0; j < 8; j++) {
        int d = ks * 32 + quad * 8 + j;
        t.s[j] = f2bf(0.125f * bf2f(qp[(size_t)d * N_ + qg]));
      }
      qf[nt][ks] = t.v;
    }
  }

  float l_i[2];
  f32x4 O[4][2];
#pragma unroll
  for (int nt = 0; nt < 2; nt++) {
    l_i[nt] = 0.f;
#pragma unroll
    for (int mt = 0; mt < 4; mt++) O[mt][nt] = f32x4{0.f, 0.f, 0.f, 0.f};
  }

  uint4 kr0, kr1, vr0, vr1;
  // stage tile 0
  {
    const unsigned short* kg = ktp + (size_t)sr0 * 512 + sc0 * 8;
    kr0 = *(const uint4*)kg;
    kr1 = *(const uint4*)(kg + (size_t)32 * 512);
    const unsigned short* vg = vp + (size_t)sr0 * N_ + sc0 * 8;
    vr0 = *(const uint4*)vg;
    vr1 = *(const uint4*)(vg + (size_t)32 * N_);
    *(uint4*)&Kt[0][sr0 * 72 + sc0 * 8] = kr0;
    *(uint4*)&Kt[0][(sr0 + 32) * 72 + sc0 * 8] = kr1;
    union { uint4 q; ushort4 h[2]; } u;
    u.q = vr0;
    *(ushort4*)&Vs[0][sr0 * 68 + sc0 * 8]     = u.h[0];
    *(ushort4*)&Vs[0][sr0 * 68 + sc0 * 8 + 4] = u.h[1];
    u.q = vr1;
    *(ushort4*)&Vs[0][(sr0 + 32) * 68 + sc0 * 8]     = u.h[0];
    *(ushort4*)&Vs[0][(sr0 + 32) * 68 + sc0 * 8 + 4] = u.h[1];
  }
  __syncthreads();

  for (int kt = 0; kt < 16; kt++) {
    const int cur = kt & 1;
    if (kt < 15) {  // issue next tile's global loads early
      const unsigned short* kg = ktp + (size_t)((kt + 1) * 64 + sr0) * 512 + sc0 * 8;
      kr0 = *(const uint4*)kg;
      kr1 = *(const uint4*)(kg + (size_t)32 * 512);
      const unsigned short* vg = vp + (size_t)sr0 * N_ + (kt + 1) * 64 + sc0 * 8;
      vr0 = *(const uint4*)vg;
      vr1 = *(const uint4*)(vg + (size_t)32 * N_);
    }

    // K A-fragments (16x16x32), b128 at 144B row stride: conflict-floor
    bf16x8 kf[4][2];
#pragma unroll
    for (int mt = 0; mt < 4; mt++) {
      int key = 16 * mt + col;
#pragma unroll
      for (int ks = 0; ks < 2; ks++)
        kf[mt][ks] = *(const bf16x8*)&Kt[cur][key * 72 + ks * 32 + quad * 8];
    }
    // V A-fragments (16x16x16), b64 at 136B row stride: conflict-free
    s16x4 vf[4][4];
#pragma unroll
    for (int mt = 0; mt < 4; mt++) {
      int d = 16 * mt + col;
#pragma unroll
      for (int kc = 0; kc < 4; kc++)
        vf[mt][kc] = *(const s16x4*)&Vs[cur][d * 68 + kc * 16 + quad * 4];
    }

    attn_tile(qf, kf, vf, O, l_i);

    if (kt < 15) {  // write staged regs to the other buffer, then barrier
      const int nb = cur ^ 1;
      *(uint4*)&Kt[nb][sr0 * 72 + sc0 * 8] = kr0;
      *(uint4*)&Kt[nb][(sr0 + 32) * 72 + sc0 * 8] = kr1;
      union { uint4 q; ushort4 h[2]; } u;
      u.q = vr0;
      *(ushort4*)&Vs[nb][sr0 * 68 + sc0 * 8]     = u.h[0];
      *(ushort4*)&Vs[nb][sr0 * 68 + sc0 * 8 + 4] = u.h[1];
      u.q = vr1;
      *(ushort4*)&Vs[nb][(sr0 + 32) * 68 + sc0 * 8]     = u.h[0];
      *(ushort4*)&Vs[nb][(sr0 + 32) * 68 + sc0 * 8 + 4] = u.h[1];
      __syncthreads();
    }
  }

#pragma unroll
  for (int nt = 0; nt < 2; nt++) {
    float ls = l_i[nt];
    ls += __shfl_xor(ls, 16, 64);
    ls += __shfl_xor(ls, 32, 64);
    float inv = 1.f / ls;
    int qg = qblk + nt * 16 + col;
    unsigned short* dst = aoT + ((size_t)b * N_ + qg) * C_ + hh * 64;
#pragma unroll
    for (int mt = 0; mt < 4; mt++) {
      union { unsigned short s[4]; ushort4 v; } o;
#pragma unroll
      for (int r = 0; r < 4; r++) o.s[r] = f2bf(O[mt][nt][r] * inv);
      *(ushort4*)(dst + mt * 16 + quad * 4) = o.v;
    }
  }
}

extern "C" void kernel_launch(void* const* d_in, const int* in_sizes, int n_in,
                              void* d_out, int out_size, void* d_ws, size_t ws_size,
                              hipStream_t stream) {
  (void)in_sizes; (void)n_in; (void)out_size; (void)ws_size;
  const float* x      = (const float*)d_in[0];
  const float* gamma  = (const float*)d_in[1];
  const float* beta   = (const float*)d_in[2];
  const float* w_qkv  = (const float*)d_in[3];
  const float* b_qkv  = (const float*)d_in[4];
  const float* w_proj = (const float*)d_in[5];
  const float* b_proj = (const float*)d_in[6];
  float* out = (float*)d_out;

  unsigned short* hT   = (unsigned short*)d_ws;                 // B*N*C bf16
  unsigned short* qkvb = hT + (size_t)B_ * N_ * C_;             // B*3C*N bf16 (K region = KT[b][n][512])
  unsigned short* aoT  = hT;                                    // reuse
  unsigned short* wqb  = qkvb + (size_t)B_ * 1536 * N_;         // 3C*C bf16
  unsigned short* wpb  = wqb + (size_t)1536 * 512;              // C*C bf16

  wconv_kernel<<<dim3(1024), dim3(256), 0, stream>>>(w_qkv, w_proj, wqb, wpb);
  gn_kernel<<<dim3(B_ * 32), dim3(256), 0, stream>>>(x, gamma, beta, hT);
  gemm_mfma<1><<<dim3(8, 12, 16), dim3(256), 0, stream>>>(
      wqb, b_qkv, hT, (const float*)nullptr, (void*)qkvb, 1536);
  attn_mfma<<<dim3(1024), dim3(256), 0, stream>>>(qkvb, aoT);
  gemm_mfma<0><<<dim3(8, 4, 16), dim3(256), 0, stream>>>(
      wpb, b_proj, aoT, x, (void*)out, 512);
}

// Round 4
// 248.645 us; speedup vs baseline: 1.2138x; 1.2138x over previous
//
#include <hip/hip_runtime.h>
#include <cstddef>

#define B_  16
#define C_  512
#define N_  1024

typedef __attribute__((ext_vector_type(8))) __bf16 bf16x8;
typedef __attribute__((ext_vector_type(4))) float f32x4;
typedef __attribute__((ext_vector_type(4))) short s16x4;

__device__ __forceinline__ unsigned short f2bf(float x) {
  unsigned u = __float_as_uint(x);
  return (unsigned short)((u + 0x7fffu + ((u >> 16) & 1u)) >> 16);
}
__device__ __forceinline__ float bf2f(unsigned short h) {
  return __uint_as_float(((unsigned)h) << 16);
}

#define GLDS16(g, l)                                                            \
  __builtin_amdgcn_global_load_lds(                                             \
      (const __attribute__((address_space(1))) void*)(g),                       \
      (__attribute__((address_space(3))) void*)(l), 16, 0, 0)

// ---------- weight fp32 -> bf16 ----------
__global__ __launch_bounds__(256) void wconv_kernel(
    const float* __restrict__ wq, const float* __restrict__ wp,
    unsigned short* __restrict__ oq, unsigned short* __restrict__ op) {
  int i = blockIdx.x * 256 + threadIdx.x;  // float4 chunks
  const float4* src; unsigned short* dst; int off;
  if (i < 196608) { src = (const float4*)wq; dst = oq; off = i; }
  else            { src = (const float4*)wp; dst = op; off = i - 196608; }
  float4 v = src[off];
  union { unsigned short s[4]; ushort4 u; } o;
  o.s[0] = f2bf(v.x); o.s[1] = f2bf(v.y);
  o.s[2] = f2bf(v.z); o.s[3] = f2bf(v.w);
  *(ushort4*)(dst + (size_t)off * 4) = o.u;
}

// ---------- GroupNorm: writes hT[b][n][c] bf16 ----------
__global__ __launch_bounds__(256) void gn_kernel(
    const float* __restrict__ x, const float* __restrict__ gamma,
    const float* __restrict__ beta, unsigned short* __restrict__ hT) {
  int bg = blockIdx.x;
  int b = bg >> 5, g = bg & 31;
  size_t base = ((size_t)b * C_ + (size_t)g * 16) * N_;
  const float4* x4 = (const float4*)(x + base);
  int tid = threadIdx.x;

  float sum = 0.f, sq = 0.f;
  float4 vv[16];
#pragma unroll
  for (int i = 0; i < 16; i++) {
    float4 v = x4[tid + i * 256];
    vv[i] = v;
    sum += v.x + v.y + v.z + v.w;
    sq  += v.x * v.x + v.y * v.y + v.z * v.z + v.w * v.w;
  }
#pragma unroll
  for (int off = 32; off > 0; off >>= 1) {
    sum += __shfl_down(sum, off, 64);
    sq  += __shfl_down(sq, off, 64);
  }
  __shared__ float sm[4], sv[4];
  int lane = tid & 63, w = tid >> 6;
  if (lane == 0) { sm[w] = sum; sv[w] = sq; }
  __syncthreads();
  if (tid == 0) {
    float s = sm[0] + sm[1] + sm[2] + sm[3];
    float q = sv[0] + sv[1] + sv[2] + sv[3];
    float mean = s * (1.f / 16384.f);
    float var  = q * (1.f / 16384.f) - mean * mean;
    sm[0] = mean;
    sv[0] = rsqrtf(var + 1e-5f);
  }
  __syncthreads();
  float mean = sm[0], rstd = sv[0];

  union { unsigned short s[16]; uint4 u[2]; } row[4];
#pragma unroll
  for (int i = 0; i < 16; i++) {
    int c = g * 16 + i;
    float ga = gamma[c] * rstd;
    float be = beta[c] - mean * ga;
    float4 v = vv[i];
    row[0].s[i] = f2bf(v.x * ga + be);
    row[1].s[i] = f2bf(v.y * ga + be);
    row[2].s[i] = f2bf(v.z * ga + be);
    row[3].s[i] = f2bf(v.w * ga + be);
  }
#pragma unroll
  for (int j = 0; j < 4; j++) {
    uint4* dst = (uint4*)(hT + ((size_t)b * N_ + 4 * tid + j) * C_ + g * 16);
    dst[0] = row[j].u[0];
    dst[1] = row[j].u[1];
  }
}

// ---------- MFMA GEMM: Out[b,m,n] = sum_k W[m,k]*InT[b,n,k] + bias[m] (+resid) ----------
// OUT_BF16==1 (QKV): K rows (m in [512,1024)) are written TRANSPOSED into the K
// region as KT[b][n][m-512], via an LDS staging buffer (rows padded to 136
// shorts) so the global writes are 256B contiguous per n.
template <int OUT_BF16>
__global__ __launch_bounds__(256) void gemm_mfma(
    const unsigned short* __restrict__ Wb, const float* __restrict__ bias,
    const unsigned short* __restrict__ InT, const float* __restrict__ resid,
    void* __restrict__ Out, int M) {
  __shared__ __align__(16) unsigned short SH[2][128 * 34];  // As=SH[0], Bs=SH[1]; epi aliases both

  const int b = blockIdx.z;
  const int n0 = blockIdx.x * 128, m0 = blockIdx.y * 128;
  const int tid = threadIdx.x;
  const int lane = tid & 63, wave = tid >> 6;
  const int col = lane & 15, quad = lane >> 4;
  const int wm = (wave >> 1) << 6, wn = (wave & 1) << 6;

  const unsigned short* Ag = Wb + (size_t)m0 * C_;
  const unsigned short* Bg = InT + ((size_t)b * N_ + n0) * C_;

  const int r0 = tid >> 2, c0 = (tid & 3) << 3;

  f32x4 acc[4][4];
#pragma unroll
  for (int i = 0; i < 4; i++)
#pragma unroll
    for (int j = 0; j < 4; j++) acc[i][j] = f32x4{0.f, 0.f, 0.f, 0.f};

  for (int k0 = 0; k0 < C_; k0 += 32) {
    __syncthreads();
    GLDS16(Ag + (size_t)r0 * C_ + k0 + c0,        &SH[0][tid * 8]);
    GLDS16(Ag + (size_t)(r0 + 64) * C_ + k0 + c0, &SH[0][(tid + 256) * 8]);
    GLDS16(Bg + (size_t)r0 * C_ + k0 + c0,        &SH[1][tid * 8]);
    GLDS16(Bg + (size_t)(r0 + 64) * C_ + k0 + c0, &SH[1][(tid + 256) * 8]);
    __syncthreads();

    bf16x8 af[4], bfr[4];
#pragma unroll
    for (int mt = 0; mt < 4; mt++)
      af[mt] = *(const bf16x8*)&SH[0][(wm + mt * 16 + col) * 32 + quad * 8];
#pragma unroll
    for (int nt = 0; nt < 4; nt++)
      bfr[nt] = *(const bf16x8*)&SH[1][(wn + nt * 16 + col) * 32 + quad * 8];
#pragma unroll
    for (int mt = 0; mt < 4; mt++)
#pragma unroll
      for (int nt = 0; nt < 4; nt++)
        acc[mt][nt] = __builtin_amdgcn_mfma_f32_16x16x32_bf16(
            af[mt], bfr[nt], acc[mt][nt], 0, 0, 0);
  }

  const bool kT = OUT_BF16 && (m0 >= 512) && (m0 < 1024);

  if (kT) {
    // Transposed K output via LDS: epi[64 n][136 shorts] per n-half.
    unsigned short* epi = &SH[0][0];
    unsigned short* kt_out =
        (unsigned short*)Out + ((size_t)b * 1536 + 512) * N_ + (m0 - 512);
#pragma unroll
    for (int hf = 0; hf < 2; hf++) {
      __syncthreads();
      if ((wave & 1) == hf) {
#pragma unroll
        for (int mt = 0; mt < 4; mt++) {
          int mloc = wm + mt * 16 + quad * 4;      // 0..127 within block tile
          int mabs = m0 + mloc;
#pragma unroll
          for (int nt = 0; nt < 4; nt++) {
            union { unsigned short s[4]; ushort4 v; } o;
#pragma unroll
            for (int r = 0; r < 4; r++)
              o.s[r] = f2bf(acc[mt][nt][r] + bias[mabs + r]);
            *(ushort4*)&epi[(nt * 16 + col) * 136 + mloc] = o.v;
          }
        }
      }
      __syncthreads();
#pragma unroll
      for (int pass = 0; pass < 4; pass++) {
        int n_l = (tid >> 4) + pass * 16;
        int ch = tid & 15;
        uint4 v = *(const uint4*)&epi[n_l * 136 + ch * 8];
        *(uint4*)(kt_out + (size_t)(n0 + hf * 64 + n_l) * 512 + ch * 8) = v;
      }
    }
    return;
  }

#pragma unroll
  for (int mt = 0; mt < 4; mt++) {
    int mbase = m0 + wm + mt * 16 + quad * 4;
#pragma unroll
    for (int nt = 0; nt < 4; nt++) {
      int n = n0 + wn + nt * 16 + col;
      if constexpr (OUT_BF16) {
#pragma unroll
        for (int r = 0; r < 4; r++) {
          float v = acc[mt][nt][r] + bias[mbase + r];
          ((unsigned short*)Out)[((size_t)b * M + mbase + r) * N_ + n] = f2bf(v);
        }
      } else {
#pragma unroll
        for (int r = 0; r < 4; r++) {
          int m = mbase + r;
          float v = acc[mt][nt][r] + bias[m];
          size_t off = ((size_t)b * M + m) * N_ + n;
          ((float*)Out)[off] = v + resid[off];
        }
      }
    }
  }
}

// ---------- MFMA flash attention, no-max softmax ----------
// Round-2 attn body (global_load_lds staging + source-side XOR chunk swizzle,
// no reg staging -> no spill) combined with the round-3 q-split grid:
// 1024 blocks (8 q-blocks x 16 b x 8 h), each wave owns 32 q rows (nt=2).
// Block index keeps bi&7 == head, so all 8 q-blocks of one (b,h) land on the
// same XCD -> K/V stay hot in that XCD's L2. One barrier per tile (race-free:
// the staged buffer was last read before the previous barrier).
__device__ __forceinline__ void attn_tile(const bf16x8 (&qf)[2][2],
                                          const bf16x8 (&kf)[4][2],
                                          const s16x4 (&vf)[4][4],
                                          f32x4 (&O)[4][2], float (&l_i)[2]) {
#pragma unroll
  for (int nt = 0; nt < 2; nt++) {
    f32x4 sf[4];
#pragma unroll
    for (int mt = 0; mt < 4; mt++) sf[mt] = f32x4{0.f, 0.f, 0.f, 0.f};
    __builtin_amdgcn_s_setprio(1);
#pragma unroll
    for (int ks = 0; ks < 2; ks++)
#pragma unroll
      for (int mt = 0; mt < 4; mt++)
        sf[mt] = __builtin_amdgcn_mfma_f32_16x16x32_bf16(
            kf[mt][ks], qf[nt][ks], sf[mt], 0, 0, 0);
    __builtin_amdgcn_s_setprio(0);

    // p = exp(s); pack to bf16 by truncation (1 v_perm per pair)
    s16x4 pb[4];
    float lsum = 0.f;
#pragma unroll
    for (int kc = 0; kc < 4; kc++) {
      float e0 = __expf(sf[kc][0]);
      float e1 = __expf(sf[kc][1]);
      float e2 = __expf(sf[kc][2]);
      float e3 = __expf(sf[kc][3]);
      lsum += (e0 + e1) + (e2 + e3);
      unsigned lo = __builtin_amdgcn_perm(__float_as_uint(e1), __float_as_uint(e0), 0x07060302u);
      unsigned hi = __builtin_amdgcn_perm(__float_as_uint(e3), __float_as_uint(e2), 0x07060302u);
      union { unsigned u[2]; s16x4 v; } t;
      t.u[0] = lo; t.u[1] = hi;
      pb[kc] = t.v;
    }
    l_i[nt] += lsum;

    __builtin_amdgcn_s_setprio(1);
#pragma unroll
    for (int kc = 0; kc < 4; kc++)
#pragma unroll
      for (int mt = 0; mt < 4; mt++)
        O[mt][nt] = __builtin_amdgcn_mfma_f32_16x16x16bf16_1k(
            vf[mt][kc], pb[kc], O[mt][nt], 0, 0, 0);
    __builtin_amdgcn_s_setprio(0);
  }
}

__global__ __launch_bounds__(256, 4) void attn_mfma(
    const unsigned short* __restrict__ qkv, unsigned short* __restrict__ aoT) {
  __shared__ __align__(16) unsigned short KtL[2][64 * 64];
  __shared__ __align__(16) unsigned short VsL[2][64 * 64];

  const int tid = threadIdx.x;
  const int wave = tid >> 6, lane = tid & 63;
  const int quad = lane >> 4, col = lane & 15;
  const int bi = blockIdx.x;
  const int hh = bi & 7, b = (bi >> 3) & 15, qb = bi >> 7;  // bi%8==head -> XCD-grouped
  const int qblk = qb * 128 + wave * 32;

  const unsigned short* qp  = qkv + ((size_t)b * 1536 + hh * 64) * N_;           // [d][N]
  const unsigned short* ktp = qkv + ((size_t)b * 1536 + 512) * N_ + hh * 64;     // [key][512]
  const unsigned short* vp  = qkv + ((size_t)b * 1536 + 1024 + hh * 64) * N_;    // [d][N]

  // staging decomposition: row within half-tile + swizzled 16B chunk
  const int sr = tid >> 3;                          // 0..31
  const int sw8 = (((tid & 7) ^ (sr & 7)) << 3);    // swizzled chunk, in shorts

  // Q B-fragments pre-scaled by 0.125 (exact: exponent shift under RNE).
  bf16x8 qf[2][2];
#pragma unroll
  for (int nt = 0; nt < 2; nt++) {
    int qg = qblk + nt * 16 + col;
#pragma unroll
    for (int ks = 0; ks < 2; ks++) {
      union { unsigned short s[8]; bf16x8 v; } t;
#pragma unroll
      for (int j = 0; j < 8; j++) {
        int d = ks * 32 + quad * 8 + j;
        t.s[j] = f2bf(0.125f * bf2f(qp[(size_t)d * N_ + qg]));
      }
      qf[nt][ks] = t.v;
    }
  }

  float l_i[2];
  f32x4 O[4][2];
#pragma unroll
  for (int nt = 0; nt < 2; nt++) {
    l_i[nt] = 0.f;
#pragma unroll
    for (int mt = 0; mt < 4; mt++) O[mt][nt] = f32x4{0.f, 0.f, 0.f, 0.f};
  }

  // stage tile 0
  {
    const unsigned short* kq = ktp + (size_t)sr * 512 + sw8;
    GLDS16(kq,                    &KtL[0][tid * 8]);
    GLDS16(kq + (size_t)32 * 512, &KtL[0][(256 + tid) * 8]);
    const unsigned short* vq = vp + (size_t)sr * N_ + sw8;
    GLDS16(vq,                    &VsL[0][tid * 8]);
    GLDS16(vq + (size_t)32 * N_,  &VsL[0][(256 + tid) * 8]);
  }
  __syncthreads();

  for (int kt = 0; kt < 16; kt++) {
    const int cur = kt & 1;
    if (kt < 15) {
      const unsigned short* kq = ktp + (size_t)((kt + 1) * 64 + sr) * 512 + sw8;
      GLDS16(kq,                    &KtL[cur ^ 1][tid * 8]);
      GLDS16(kq + (size_t)32 * 512, &KtL[cur ^ 1][(256 + tid) * 8]);
      const unsigned short* vq = vp + (size_t)sr * N_ + (kt + 1) * 64 + sw8;
      GLDS16(vq,                    &VsL[cur ^ 1][tid * 8]);
      GLDS16(vq + (size_t)32 * N_,  &VsL[cur ^ 1][(256 + tid) * 8]);
    }

    // K A-fragments (16x16x32): b128, swizzle-matched
    bf16x8 kf[4][2];
#pragma unroll
    for (int mt = 0; mt < 4; mt++) {
      int key = 16 * mt + col;
#pragma unroll
      for (int ks = 0; ks < 2; ks++)
        kf[mt][ks] = *(const bf16x8*)
            &KtL[cur][key * 64 + (((ks * 4 + quad) ^ (col & 7)) << 3)];
    }
    // V A-fragments (16x16x16): b64, swizzle-matched at 8B granularity
    s16x4 vf[4][4];
#pragma unroll
    for (int mt = 0; mt < 4; mt++) {
      int d = 16 * mt + col;
#pragma unroll
      for (int kc = 0; kc < 4; kc++)
        vf[mt][kc] = *(const s16x4*)
            &VsL[cur][d * 64 + (((kc * 4 + quad) ^ ((col & 7) << 1)) << 2)];
    }

    attn_tile(qf, kf, vf, O, l_i);

    if (kt < 15) __syncthreads();
  }

#pragma unroll
  for (int nt = 0; nt < 2; nt++) {
    float ls = l_i[nt];
    ls += __shfl_xor(ls, 16, 64);
    ls += __shfl_xor(ls, 32, 64);
    float inv = 1.f / ls;
    int qg = qblk + nt * 16 + col;
    unsigned short* dst = aoT + ((size_t)b * N_ + qg) * C_ + hh * 64;
#pragma unroll
    for (int mt = 0; mt < 4; mt++) {
      union { unsigned short s[4]; ushort4 v; } o;
#pragma unroll
      for (int r = 0; r < 4; r++) o.s[r] = f2bf(O[mt][nt][r] * inv);
      *(ushort4*)(dst + mt * 16 + quad * 4) = o.v;
    }
  }
}

extern "C" void kernel_launch(void* const* d_in, const int* in_sizes, int n_in,
                              void* d_out, int out_size, void* d_ws, size_t ws_size,
                              hipStream_t stream) {
  (void)in_sizes; (void)n_in; (void)out_size; (void)ws_size;
  const float* x      = (const float*)d_in[0];
  const float* gamma  = (const float*)d_in[1];
  const float* beta   = (const float*)d_in[2];
  const float* w_qkv  = (const float*)d_in[3];
  const float* b_qkv  = (const float*)d_in[4];
  const float* w_proj = (const float*)d_in[5];
  const float* b_proj = (const float*)d_in[6];
  float* out = (float*)d_out;

  unsigned short* hT   = (unsigned short*)d_ws;                 // B*N*C bf16
  unsigned short* qkvb = hT + (size_t)B_ * N_ * C_;             // B*3C*N bf16 (K region = KT[b][n][512])
  unsigned short* aoT  = hT;                                    // reuse
  unsigned short* wqb  = qkvb + (size_t)B_ * 1536 * N_;         // 3C*C bf16
  unsigned short* wpb  = wqb + (size_t)1536 * 512;              // C*C bf16

  wconv_kernel<<<dim3(1024), dim3(256), 0, stream>>>(w_qkv, w_proj, wqb, wpb);
  gn_kernel<<<dim3(B_ * 32), dim3(256), 0, stream>>>(x, gamma, beta, hT);
  gemm_mfma<1><<<dim3(8, 12, 16), dim3(256), 0, stream>>>(
      wqb, b_qkv, hT, (const float*)nullptr, (void*)qkvb, 1536);
  attn_mfma<<<dim3(1024), dim3(256), 0, stream>>>(qkvb, aoT);
  gemm_mfma<0><<<dim3(8, 4, 16), dim3(256), 0, stream>>>(
      wpb, b_proj, aoT, x, (void*)out, 512);
}

// Round 5
// 217.065 us; speedup vs baseline: 1.3904x; 1.1455x over previous
//
#include <hip/hip_runtime.h>
#include <cstddef>

#define B_  16
#define C_  512
#define N_  1024

typedef __attribute__((ext_vector_type(8))) __bf16 bf16x8;
typedef __attribute__((ext_vector_type(4))) float f32x4;
typedef __attribute__((ext_vector_type(4))) short s16x4;

__device__ __forceinline__ unsigned short f2bf(float x) {
  unsigned u = __float_as_uint(x);
  return (unsigned short)((u + 0x7fffu + ((u >> 16) & 1u)) >> 16);
}
__device__ __forceinline__ float bf2f(unsigned short h) {
  return __uint_as_float(((unsigned)h) << 16);
}

#define GLDS16(g, l)                                                            \
  __builtin_amdgcn_global_load_lds(                                             \
      (const __attribute__((address_space(1))) void*)(g),                       \
      (__attribute__((address_space(3))) void*)(l), 16, 0, 0)

// ---------- weight fp32 -> bf16 ----------
__global__ __launch_bounds__(256) void wconv_kernel(
    const float* __restrict__ wq, const float* __restrict__ wp,
    unsigned short* __restrict__ oq, unsigned short* __restrict__ op) {
  int i = blockIdx.x * 256 + threadIdx.x;  // float4 chunks
  const float4* src; unsigned short* dst; int off;
  if (i < 196608) { src = (const float4*)wq; dst = oq; off = i; }
  else            { src = (const float4*)wp; dst = op; off = i - 196608; }
  float4 v = src[off];
  union { unsigned short s[4]; ushort4 u; } o;
  o.s[0] = f2bf(v.x); o.s[1] = f2bf(v.y);
  o.s[2] = f2bf(v.z); o.s[3] = f2bf(v.w);
  *(ushort4*)(dst + (size_t)off * 4) = o.u;
}

// ---------- GroupNorm: writes hT[b][n][c] bf16 ----------
__global__ __launch_bounds__(256) void gn_kernel(
    const float* __restrict__ x, const float* __restrict__ gamma,
    const float* __restrict__ beta, unsigned short* __restrict__ hT) {
  int bg = blockIdx.x;
  int b = bg >> 5, g = bg & 31;
  size_t base = ((size_t)b * C_ + (size_t)g * 16) * N_;
  const float4* x4 = (const float4*)(x + base);
  int tid = threadIdx.x;

  float sum = 0.f, sq = 0.f;
  float4 vv[16];
#pragma unroll
  for (int i = 0; i < 16; i++) {
    float4 v = x4[tid + i * 256];
    vv[i] = v;
    sum += v.x + v.y + v.z + v.w;
    sq  += v.x * v.x + v.y * v.y + v.z * v.z + v.w * v.w;
  }
#pragma unroll
  for (int off = 32; off > 0; off >>= 1) {
    sum += __shfl_down(sum, off, 64);
    sq  += __shfl_down(sq, off, 64);
  }
  __shared__ float sm[4], sv[4];
  int lane = tid & 63, w = tid >> 6;
  if (lane == 0) { sm[w] = sum; sv[w] = sq; }
  __syncthreads();
  if (tid == 0) {
    float s = sm[0] + sm[1] + sm[2] + sm[3];
    float q = sv[0] + sv[1] + sv[2] + sv[3];
    float mean = s * (1.f / 16384.f);
    float var  = q * (1.f / 16384.f) - mean * mean;
    sm[0] = mean;
    sv[0] = rsqrtf(var + 1e-5f);
  }
  __syncthreads();
  float mean = sm[0], rstd = sv[0];

  union { unsigned short s[16]; uint4 u[2]; } row[4];
#pragma unroll
  for (int i = 0; i < 16; i++) {
    int c = g * 16 + i;
    float ga = gamma[c] * rstd;
    float be = beta[c] - mean * ga;
    float4 v = vv[i];
    row[0].s[i] = f2bf(v.x * ga + be);
    row[1].s[i] = f2bf(v.y * ga + be);
    row[2].s[i] = f2bf(v.z * ga + be);
    row[3].s[i] = f2bf(v.w * ga + be);
  }
#pragma unroll
  for (int j = 0; j < 4; j++) {
    uint4* dst = (uint4*)(hT + ((size_t)b * N_ + 4 * tid + j) * C_ + g * 16);
    dst[0] = row[j].u[0];
    dst[1] = row[j].u[1];
  }
}

// ---------- MFMA GEMM: Out[b,m,n] = sum_k W[m,k]*InT[b,n,k] + bias[m] (+resid) ----------
// OUT_BF16==1 (QKV): K rows (m in [512,1024)) are written TRANSPOSED into the K
// region as KT[b][n][m-512], via an LDS staging buffer (rows padded to 136
// shorts) so the global writes are 256B contiguous per n.
template <int OUT_BF16>
__global__ __launch_bounds__(256) void gemm_mfma(
    const unsigned short* __restrict__ Wb, const float* __restrict__ bias,
    const unsigned short* __restrict__ InT, const float* __restrict__ resid,
    void* __restrict__ Out, int M) {
  __shared__ __align__(16) unsigned short SH[2][128 * 34];  // As=SH[0], Bs=SH[1]; epi aliases both

  const int b = blockIdx.z;
  const int n0 = blockIdx.x * 128, m0 = blockIdx.y * 128;
  const int tid = threadIdx.x;
  const int lane = tid & 63, wave = tid >> 6;
  const int col = lane & 15, quad = lane >> 4;
  const int wm = (wave >> 1) << 6, wn = (wave & 1) << 6;

  const unsigned short* Ag = Wb + (size_t)m0 * C_;
  const unsigned short* Bg = InT + ((size_t)b * N_ + n0) * C_;

  const int r0 = tid >> 2, c0 = (tid & 3) << 3;

  f32x4 acc[4][4];
#pragma unroll
  for (int i = 0; i < 4; i++)
#pragma unroll
    for (int j = 0; j < 4; j++) acc[i][j] = f32x4{0.f, 0.f, 0.f, 0.f};

  for (int k0 = 0; k0 < C_; k0 += 32) {
    __syncthreads();
    GLDS16(Ag + (size_t)r0 * C_ + k0 + c0,        &SH[0][tid * 8]);
    GLDS16(Ag + (size_t)(r0 + 64) * C_ + k0 + c0, &SH[0][(tid + 256) * 8]);
    GLDS16(Bg + (size_t)r0 * C_ + k0 + c0,        &SH[1][tid * 8]);
    GLDS16(Bg + (size_t)(r0 + 64) * C_ + k0 + c0, &SH[1][(tid + 256) * 8]);
    __syncthreads();

    bf16x8 af[4], bfr[4];
#pragma unroll
    for (int mt = 0; mt < 4; mt++)
      af[mt] = *(const bf16x8*)&SH[0][(wm + mt * 16 + col) * 32 + quad * 8];
#pragma unroll
    for (int nt = 0; nt < 4; nt++)
      bfr[nt] = *(const bf16x8*)&SH[1][(wn + nt * 16 + col) * 32 + quad * 8];
#pragma unroll
    for (int mt = 0; mt < 4; mt++)
#pragma unroll
      for (int nt = 0; nt < 4; nt++)
        acc[mt][nt] = __builtin_amdgcn_mfma_f32_16x16x32_bf16(
            af[mt], bfr[nt], acc[mt][nt], 0, 0, 0);
  }

  const bool kT = OUT_BF16 && (m0 >= 512) && (m0 < 1024);

  if (kT) {
    // Transposed K output via LDS: epi[64 n][136 shorts] per n-half.
    unsigned short* epi = &SH[0][0];
    unsigned short* kt_out =
        (unsigned short*)Out + ((size_t)b * 1536 + 512) * N_ + (m0 - 512);
#pragma unroll
    for (int hf = 0; hf < 2; hf++) {
      __syncthreads();
      if ((wave & 1) == hf) {
#pragma unroll
        for (int mt = 0; mt < 4; mt++) {
          int mloc = wm + mt * 16 + quad * 4;      // 0..127 within block tile
          int mabs = m0 + mloc;
#pragma unroll
          for (int nt = 0; nt < 4; nt++) {
            union { unsigned short s[4]; ushort4 v; } o;
#pragma unroll
            for (int r = 0; r < 4; r++)
              o.s[r] = f2bf(acc[mt][nt][r] + bias[mabs + r]);
            *(ushort4*)&epi[(nt * 16 + col) * 136 + mloc] = o.v;
          }
        }
      }
      __syncthreads();
#pragma unroll
      for (int pass = 0; pass < 4; pass++) {
        int n_l = (tid >> 4) + pass * 16;
        int ch = tid & 15;
        uint4 v = *(const uint4*)&epi[n_l * 136 + ch * 8];
        *(uint4*)(kt_out + (size_t)(n0 + hf * 64 + n_l) * 512 + ch * 8) = v;
      }
    }
    return;
  }

#pragma unroll
  for (int mt = 0; mt < 4; mt++) {
    int mbase = m0 + wm + mt * 16 + quad * 4;
#pragma unroll
    for (int nt = 0; nt < 4; nt++) {
      int n = n0 + wn + nt * 16 + col;
      if constexpr (OUT_BF16) {
#pragma unroll
        for (int r = 0; r < 4; r++) {
          float v = acc[mt][nt][r] + bias[mbase + r];
          ((unsigned short*)Out)[((size_t)b * M + mbase + r) * N_ + n] = f2bf(v);
        }
      } else {
#pragma unroll
        for (int r = 0; r < 4; r++) {
          int m = mbase + r;
          float v = acc[mt][nt][r] + bias[m];
          size_t off = ((size_t)b * M + m) * N_ + n;
          ((float*)Out)[off] = v + resid[off];
        }
      }
    }
  }
}

// ---------- MFMA flash attention, no-max softmax ----------
// global_load_lds staging + source-side XOR chunk swizzle (round-2 body),
// q-split grid: 1024 blocks (8 q-blocks x 16 b x 8 h), each wave owns 32 q
// rows (nt=2). bi&7 == head keeps all 8 q-blocks of one (b,h) on one XCD.
// __launch_bounds__(256,2): (256,4) forced the 64-VGPR tier and spilled ~80
// regs of state to scratch (rounds 3+4, +126MB HBM traffic); 116 VGPR still
// allows 4 waves/SIMD (<128 cliff), so 4 blocks/CU co-resident at runtime.
__device__ __forceinline__ void attn_tile(const bf16x8 (&qf)[2][2],
                                          const bf16x8 (&kf)[4][2],
                                          const s16x4 (&vf)[4][4],
                                          f32x4 (&O)[4][2], float (&l_i)[2]) {
#pragma unroll
  for (int nt = 0; nt < 2; nt++) {
    f32x4 sf[4];
#pragma unroll
    for (int mt = 0; mt < 4; mt++) sf[mt] = f32x4{0.f, 0.f, 0.f, 0.f};
    __builtin_amdgcn_s_setprio(1);
#pragma unroll
    for (int ks = 0; ks < 2; ks++)
#pragma unroll
      for (int mt = 0; mt < 4; mt++)
        sf[mt] = __builtin_amdgcn_mfma_f32_16x16x32_bf16(
            kf[mt][ks], qf[nt][ks], sf[mt], 0, 0, 0);
    __builtin_amdgcn_s_setprio(0);

    // p = exp(s); pack to bf16 by truncation (1 v_perm per pair)
    s16x4 pb[4];
    float lsum = 0.f;
#pragma unroll
    for (int kc = 0; kc < 4; kc++) {
      float e0 = __expf(sf[kc][0]);
      float e1 = __expf(sf[kc][1]);
      float e2 = __expf(sf[kc][2]);
      float e3 = __expf(sf[kc][3]);
      lsum += (e0 + e1) + (e2 + e3);
      unsigned lo = __builtin_amdgcn_perm(__float_as_uint(e1), __float_as_uint(e0), 0x07060302u);
      unsigned hi = __builtin_amdgcn_perm(__float_as_uint(e3), __float_as_uint(e2), 0x07060302u);
      union { unsigned u[2]; s16x4 v; } t;
      t.u[0] = lo; t.u[1] = hi;
      pb[kc] = t.v;
    }
    l_i[nt] += lsum;

    __builtin_amdgcn_s_setprio(1);
#pragma unroll
    for (int kc = 0; kc < 4; kc++)
#pragma unroll
      for (int mt = 0; mt < 4; mt++)
        O[mt][nt] = __builtin_amdgcn_mfma_f32_16x16x16bf16_1k(
            vf[mt][kc], pb[kc], O[mt][nt], 0, 0, 0);
    __builtin_amdgcn_s_setprio(0);
  }
}

__global__ __launch_bounds__(256, 2) void attn_mfma(
    const unsigned short* __restrict__ qkv, unsigned short* __restrict__ aoT) {
  __shared__ __align__(16) unsigned short KtL[2][64 * 64];
  __shared__ __align__(16) unsigned short VsL[2][64 * 64];

  const int tid = threadIdx.x;
  const int wave = tid >> 6, lane = tid & 63;
  const int quad = lane >> 4, col = lane & 15;
  const int bi = blockIdx.x;
  const int hh = bi & 7, b = (bi >> 3) & 15, qb = bi >> 7;  // bi%8==head -> XCD-grouped
  const int qblk = qb * 128 + wave * 32;

  const unsigned short* qp  = qkv + ((size_t)b * 1536 + hh * 64) * N_;           // [d][N]
  const unsigned short* ktp = qkv + ((size_t)b * 1536 + 512) * N_ + hh * 64;     // [key][512]
  const unsigned short* vp  = qkv + ((size_t)b * 1536 + 1024 + hh * 64) * N_;    // [d][N]

  // staging decomposition: row within half-tile + swizzled 16B chunk
  const int sr = tid >> 3;                          // 0..31
  const int sw8 = (((tid & 7) ^ (sr & 7)) << 3);    // swizzled chunk, in shorts

  // Q B-fragments pre-scaled by 0.125 (exact: exponent shift under RNE).
  bf16x8 qf[2][2];
#pragma unroll
  for (int nt = 0; nt < 2; nt++) {
    int qg = qblk + nt * 16 + col;
#pragma unroll
    for (int ks = 0; ks < 2; ks++) {
      union { unsigned short s[8]; bf16x8 v; } t;
#pragma unroll
      for (int j = 0; j < 8; j++) {
        int d = ks * 32 + quad * 8 + j;
        t.s[j] = f2bf(0.125f * bf2f(qp[(size_t)d * N_ + qg]));
      }
      qf[nt][ks] = t.v;
    }
  }

  float l_i[2];
  f32x4 O[4][2];
#pragma unroll
  for (int nt = 0; nt < 2; nt++) {
    l_i[nt] = 0.f;
#pragma unroll
    for (int mt = 0; mt < 4; mt++) O[mt][nt] = f32x4{0.f, 0.f, 0.f, 0.f};
  }

  // stage tile 0
  {
    const unsigned short* kq = ktp + (size_t)sr * 512 + sw8;
    GLDS16(kq,                    &KtL[0][tid * 8]);
    GLDS16(kq + (size_t)32 * 512, &KtL[0][(256 + tid) * 8]);
    const unsigned short* vq = vp + (size_t)sr * N_ + sw8;
    GLDS16(vq,                    &VsL[0][tid * 8]);
    GLDS16(vq + (size_t)32 * N_,  &VsL[0][(256 + tid) * 8]);
  }
  __syncthreads();

  for (int kt = 0; kt < 16; kt++) {
    const int cur = kt & 1;
    if (kt < 15) {
      const unsigned short* kq = ktp + (size_t)((kt + 1) * 64 + sr) * 512 + sw8;
      GLDS16(kq,                    &KtL[cur ^ 1][tid * 8]);
      GLDS16(kq + (size_t)32 * 512, &KtL[cur ^ 1][(256 + tid) * 8]);
      const unsigned short* vq = vp + (size_t)sr * N_ + (kt + 1) * 64 + sw8;
      GLDS16(vq,                    &VsL[cur ^ 1][tid * 8]);
      GLDS16(vq + (size_t)32 * N_,  &VsL[cur ^ 1][(256 + tid) * 8]);
    }

    // K A-fragments (16x16x32): b128, swizzle-matched
    bf16x8 kf[4][2];
#pragma unroll
    for (int mt = 0; mt < 4; mt++) {
      int key = 16 * mt + col;
#pragma unroll
      for (int ks = 0; ks < 2; ks++)
        kf[mt][ks] = *(const bf16x8*)
            &KtL[cur][key * 64 + (((ks * 4 + quad) ^ (col & 7)) << 3)];
    }
    // V A-fragments (16x16x16): b64, swizzle-matched at 8B granularity
    s16x4 vf[4][4];
#pragma unroll
    for (int mt = 0; mt < 4; mt++) {
      int d = 16 * mt + col;
#pragma unroll
      for (int kc = 0; kc < 4; kc++)
        vf[mt][kc] = *(const s16x4*)
            &VsL[cur][d * 64 + (((kc * 4 + quad) ^ ((col & 7) << 1)) << 2)];
    }

    attn_tile(qf, kf, vf, O, l_i);

    if (kt < 15) __syncthreads();
  }

#pragma unroll
  for (int nt = 0; nt < 2; nt++) {
    float ls = l_i[nt];
    ls += __shfl_xor(ls, 16, 64);
    ls += __shfl_xor(ls, 32, 64);
    float inv = 1.f / ls;
    int qg = qblk + nt * 16 + col;
    unsigned short* dst = aoT + ((size_t)b * N_ + qg) * C_ + hh * 64;
#pragma unroll
    for (int mt = 0; mt < 4; mt++) {
      union { unsigned short s[4]; ushort4 v; } o;
#pragma unroll
      for (int r = 0; r < 4; r++) o.s[r] = f2bf(O[mt][nt][r] * inv);
      *(ushort4*)(dst + mt * 16 + quad * 4) = o.v;
    }
  }
}

extern "C" void kernel_launch(void* const* d_in, const int* in_sizes, int n_in,
                              void* d_out, int out_size, void* d_ws, size_t ws_size,
                              hipStream_t stream) {
  (void)in_sizes; (void)n_in; (void)out_size; (void)ws_size;
  const float* x      = (const float*)d_in[0];
  const float* gamma  = (const float*)d_in[1];
  const float* beta   = (const float*)d_in[2];
  const float* w_qkv  = (const float*)d_in[3];
  const float* b_qkv  = (const float*)d_in[4];
  const float* w_proj = (const float*)d_in[5];
  const float* b_proj = (const float*)d_in[6];
  float* out = (float*)d_out;

  unsigned short* hT   = (unsigned short*)d_ws;                 // B*N*C bf16
  unsigned short* qkvb = hT + (size_t)B_ * N_ * C_;             // B*3C*N bf16 (K region = KT[b][n][512])
  unsigned short* aoT  = hT;                                    // reuse
  unsigned short* wqb  = qkvb + (size_t)B_ * 1536 * N_;         // 3C*C bf16
  unsigned short* wpb  = wqb + (size_t)1536 * 512;              // C*C bf16

  wconv_kernel<<<dim3(1024), dim3(256), 0, stream>>>(w_qkv, w_proj, wqb, wpb);
  gn_kernel<<<dim3(B_ * 32), dim3(256), 0, stream>>>(x, gamma, beta, hT);
  gemm_mfma<1><<<dim3(8, 12, 16), dim3(256), 0, stream>>>(
      wqb, b_qkv, hT, (const float*)nullptr, (void*)qkvb, 1536);
  attn_mfma<<<dim3(1024), dim3(256), 0, stream>>>(qkvb, aoT);
  gemm_mfma<0><<<dim3(8, 4, 16), dim3(256), 0, stream>>>(
      wpb, b_proj, aoT, x, (void*)out, 512);
}